// Round 6
// baseline (482.707 us; speedup 1.0000x reference)
//
#include <hip/hip_runtime.h>
#include <stdint.h>

typedef _Float16 half8 __attribute__((ext_vector_type(8)));   // fp16 MFMA frag (4 VGPRs)
typedef __attribute__((ext_vector_type(4))) float f32x4;      // MFMA accumulator
typedef __attribute__((ext_vector_type(8))) unsigned short us8;

__device__ inline unsigned short f2h(float x) {
  _Float16 h = (_Float16)x;                 // v_cvt_f16_f32, RNE
  return __builtin_bit_cast(unsigned short, h);
}

// ---- async global->LDS, 16B per lane ----
__device__ inline void ld16(const unsigned short* g, unsigned short* l) {
  __builtin_amdgcn_global_load_lds(
      (const __attribute__((address_space(1))) unsigned int*)g,
      (__attribute__((address_space(3))) unsigned int*)l, 16, 0, 0);
}

// ---- fp32 -> fp16 cast, 8 elems/thread (whole tensor) ----
__global__ void k_cast16(const float* __restrict__ in, unsigned short* __restrict__ o, long n8) {
  long i = (long)blockIdx.x * blockDim.x + threadIdx.x;
  if (i >= n8) return;
  float4 a = ((const float4*)in)[i * 2];
  float4 b = ((const float4*)in)[i * 2 + 1];
  us8 h;
  h[0] = f2h(a.x); h[1] = f2h(a.y); h[2] = f2h(a.z); h[3] = f2h(a.w);
  h[4] = f2h(b.x); h[5] = f2h(b.y); h[6] = f2h(b.z); h[7] = f2h(b.w);
  *(us8*)(o + i * 8) = h;
}

// ---- fp32 -> fp16 cast of a K-row chunk per batch ----
__global__ void k_cast16c(const float* __restrict__ in, unsigned short* __restrict__ o,
                          int Kn, int Dn, int k0c, int Kc) {
  const long i = (long)blockIdx.x * blockDim.x + threadIdx.x;
  const long cols8 = (long)Kc * Dn / 8;
  const int b = (int)(i / cols8);
  const long j = i - (long)b * cols8;
  const float* p = in + (long)b * Kn * Dn + (long)k0c * Dn + j * 8;
  float4 a = *(const float4*)p;
  float4 c = *(const float4*)(p + 4);
  us8 h;
  h[0] = f2h(a.x); h[1] = f2h(a.y); h[2] = f2h(a.z); h[3] = f2h(a.w);
  h[4] = f2h(c.x); h[5] = f2h(c.y); h[6] = f2h(c.z); h[7] = f2h(c.w);
  *(us8*)(o + (long)b * Kc * Dn + j * 8) = h;
}

// ---- V [K x D] fp32 -> VT-chunk [D x Kc] fp16 (per batch, k-chunk) ----
__global__ void k_transpose16(const float* __restrict__ V, unsigned short* __restrict__ VT,
                              int Kn, int Dn, int k0c, int Kc) {
  __shared__ unsigned short t[64][65];
  const int b = blockIdx.z;
  const int k0 = blockIdx.x * 64, d0 = blockIdx.y * 64;
  const int c = threadIdx.x & 63, rr = threadIdx.x >> 6;
  const float* pV = V + (long)b * Kn * Dn;
  unsigned short* pT = VT + (long)b * Dn * Kc;
#pragma unroll
  for (int i = 0; i < 16; ++i) {
    int r = rr + i * 4;
    t[r][c] = f2h(pV[(long)(k0c + k0 + r) * Dn + d0 + c]);
  }
  __syncthreads();
#pragma unroll
  for (int i = 0; i < 16; ++i) {
    int r = rr + i * 4;
    pT[(long)(d0 + r) * Kc + k0 + c] = t[c][r];
  }
}

// ============================================================================
// 128x128-tile GEMM, 4 waves (2M x 2N), BK=32, 4 LDS buffers (64 KiB total)
// -> 2 BLOCKS / CU co-resident (the R0-measured full-GPU concurrency win),
// combined with R2's pipelined 1-barrier + counted-vmcnt(4) K-loop (the
// R2-measured inner-loop win). T1 XCD swizzle, T2 LDS XOR swizzle, T5
// setprio. C[M,N] (+)= A[M,Kin] * B[N,Kin]^T, fp16 in, fp32 out.
// STATS==1: per-(b, row-tile, wave-row) column max/sumexp partials, 32 slots.
// ============================================================================

#define SBAR() __builtin_amdgcn_s_barrier()
#define SCHED0() __builtin_amdgcn_sched_barrier(0)
#define VMC(n) do { asm volatile("s_waitcnt vmcnt(" #n ")" ::: "memory"); } while (0)

template <int STATS, int ACC>
__launch_bounds__(256, 2)
__global__ void k_gemm_bt(const unsigned short* __restrict__ A,
                          const unsigned short* __restrict__ B,
                          float* __restrict__ C, float2* __restrict__ ps,
                          int N, int Kin, long sA, long sB, long sC) {
  // 4 buffers x (A 128x32 + B 128x32) fp16 = 4 x 16 KiB = 64 KiB
  __shared__ unsigned short sAb[4][128 * 32];
  __shared__ unsigned short sBb[4][128 * 32];

  const int tid = threadIdx.x;
  const int lane = tid & 63, wave = tid >> 6;
  const int wr = wave >> 1, wc = wave & 1;   // 2 x 2 wave grid; wave owns 64x64
  const int l15 = lane & 15;

  // ---- T1: bijective XCD swizzle (all grids here have nwg % 8 == 0) ----
  const int nx = gridDim.x, ny = gridDim.y;
  int wg = ((int)blockIdx.z * ny + blockIdx.y) * nx + blockIdx.x;
  const int nwg = nx * ny * (int)gridDim.z;
  wg = (wg & 7) * (nwg >> 3) + (wg >> 3);
  const int tn = wg % nx, tm = (wg / nx) % ny, b = wg / (nx * ny);

  const unsigned short* pA = A + b * sA + (long)tm * 128 * Kin;
  const unsigned short* pB = B + b * sB + (long)tn * 128 * Kin;
  float* pC = C + b * sC;

  // ---- staging: linear LDS dest, inverse-swizzled global source (T2) ----
  const int rlo = tid >> 2;                                  // dest row 0..63
  const int csw = ((tid & 3) * 8) ^ (((rlo >> 1) & 3) << 3); // src col chunk
  const long ga = (long)rlo * Kin + csw;
  const long gh = (long)64 * Kin;                            // row-half stride

  // ---- fragment ds_read offsets (same XOR on the read side) ----
  const int ksw = ((lane >> 4) * 8) ^ (((l15 >> 1) & 3) << 3);
  const int aoff = (wr * 64 + l15) * 32 + ksw;   // + m*512 per 16-row step
  const int boff = (wc * 64 + l15) * 32 + ksw;   // + n*512 per 16-row step

#define STG(t, q) do { \
    ld16(pA + ga + (long)(t) * 32, &sAb[q][tid * 8]); \
    ld16(pA + ga + gh + (long)(t) * 32, &sAb[q][2048 + tid * 8]); \
    ld16(pB + ga + (long)(t) * 32, &sBb[q][tid * 8]); \
    ld16(pB + ga + gh + (long)(t) * 32, &sBb[q][2048 + tid * 8]); } while (0)

#define LDA8(q, m) (*(const half8*)&sAb[q][aoff + (m) * 512])
#define LDB8(q, n) (*(const half8*)&sBb[q][boff + (n) * 512])

  f32x4 acc[4][4];
#pragma unroll
  for (int i = 0; i < 4; ++i)
#pragma unroll
    for (int j = 0; j < 4; ++j)
#pragma unroll
      for (int r = 0; r < 4; ++r) acc[i][j][r] = 0.f;

  // frag sets: aF/bL double-buffered across tiles; bH (n=2,3) single
  half8 aF[2][4], bL[2][2], bH[2];

#define READ_LO(s, q) \
  aF[s][0] = LDA8(q, 0); aF[s][1] = LDA8(q, 1); aF[s][2] = LDA8(q, 2); aF[s][3] = LDA8(q, 3); \
  bL[s][0] = LDB8(q, 0); bL[s][1] = LDB8(q, 1);

#define READ_BHI(q) \
  bH[0] = LDB8(q, 2); bH[1] = LDB8(q, 3);

#define MFMA_LO(s) \
  __builtin_amdgcn_s_setprio(1); \
  acc[0][0] = __builtin_amdgcn_mfma_f32_16x16x32_f16(aF[s][0], bL[s][0], acc[0][0], 0, 0, 0); \
  acc[0][1] = __builtin_amdgcn_mfma_f32_16x16x32_f16(aF[s][0], bL[s][1], acc[0][1], 0, 0, 0); \
  acc[1][0] = __builtin_amdgcn_mfma_f32_16x16x32_f16(aF[s][1], bL[s][0], acc[1][0], 0, 0, 0); \
  acc[1][1] = __builtin_amdgcn_mfma_f32_16x16x32_f16(aF[s][1], bL[s][1], acc[1][1], 0, 0, 0); \
  acc[2][0] = __builtin_amdgcn_mfma_f32_16x16x32_f16(aF[s][2], bL[s][0], acc[2][0], 0, 0, 0); \
  acc[2][1] = __builtin_amdgcn_mfma_f32_16x16x32_f16(aF[s][2], bL[s][1], acc[2][1], 0, 0, 0); \
  acc[3][0] = __builtin_amdgcn_mfma_f32_16x16x32_f16(aF[s][3], bL[s][0], acc[3][0], 0, 0, 0); \
  acc[3][1] = __builtin_amdgcn_mfma_f32_16x16x32_f16(aF[s][3], bL[s][1], acc[3][1], 0, 0, 0); \
  __builtin_amdgcn_s_setprio(0);

#define MFMA_HI(s) \
  __builtin_amdgcn_s_setprio(1); \
  acc[0][2] = __builtin_amdgcn_mfma_f32_16x16x32_f16(aF[s][0], bH[0], acc[0][2], 0, 0, 0); \
  acc[0][3] = __builtin_amdgcn_mfma_f32_16x16x32_f16(aF[s][0], bH[1], acc[0][3], 0, 0, 0); \
  acc[1][2] = __builtin_amdgcn_mfma_f32_16x16x32_f16(aF[s][1], bH[0], acc[1][2], 0, 0, 0); \
  acc[1][3] = __builtin_amdgcn_mfma_f32_16x16x32_f16(aF[s][1], bH[1], acc[1][3], 0, 0, 0); \
  acc[2][2] = __builtin_amdgcn_mfma_f32_16x16x32_f16(aF[s][2], bH[0], acc[2][2], 0, 0, 0); \
  acc[2][3] = __builtin_amdgcn_mfma_f32_16x16x32_f16(aF[s][2], bH[1], acc[2][3], 0, 0, 0); \
  acc[3][2] = __builtin_amdgcn_mfma_f32_16x16x32_f16(aF[s][3], bH[0], acc[3][2], 0, 0, 0); \
  acc[3][3] = __builtin_amdgcn_mfma_f32_16x16x32_f16(aF[s][3], bH[1], acc[3][3], 0, 0, 0); \
  __builtin_amdgcn_s_setprio(0);

  // Per tile t (set s = t&1): R2 ledger at 128^2 scale — 4 loads/tile,
  // 2 tiles in flight, steady-state wait vmcnt(4); ONE barrier/tile.
  // WAR: buf (t+2)&3 (tile t-2) last read at start of tile t-2, >=2
  // barriers before STG(t+2) here. bH single-set: read at tile start,
  // consumed at tile end, rewritten only next tile.
#define TILE_MAIN(t, s, sn) \
  READ_BHI((t) & 3); \
  STG((t) + 2, ((t) + 2) & 3); \
  MFMA_LO(s) \
  VMC(4); SBAR(); SCHED0(); \
  READ_LO(sn, ((t) + 1) & 3); \
  MFMA_HI(s)

  const int nt = Kin >> 5;   // K-tiles of 32 (even, >= 4)

  STG(0, 0);
  STG(1, 1);
  VMC(4); SBAR(); SCHED0();
  READ_LO(0, 0);

  for (int t = 0; t + 3 < nt; t += 2) {
    TILE_MAIN(t, 0, 1);
    TILE_MAIN(t + 1, 1, 0);
  }
  // peeled last pair (tiles nt-2, nt-1): no staging; drain vmcnt fully
  {
    READ_BHI((nt - 2) & 3);
    MFMA_LO(0)
    VMC(0); SBAR(); SCHED0();
    READ_LO(1, (nt - 1) & 3);
    MFMA_HI(0)
    READ_BHI((nt - 1) & 3);
    MFMA_LO(1)
    MFMA_HI(1)
  }

  // ---- epilogue: C write (C/D layout: col=lane&15, row=(lane>>4)*4+r) ----
  const int crow0 = tm * 128 + wr * 64 + (lane >> 4) * 4;
  const int ccol0 = tn * 128 + wc * 64 + l15;
#pragma unroll
  for (int m = 0; m < 4; ++m)
#pragma unroll
    for (int n = 0; n < 4; ++n)
#pragma unroll
      for (int r = 0; r < 4; ++r) {
        long idx = (long)(crow0 + m * 16 + r) * N + ccol0 + n * 16;
        if constexpr (ACC) pC[idx] += acc[m][n][r];
        else pC[idx] = acc[m][n][r];
      }

  if constexpr (STATS) {
    // per-wave column stats over this wave's 64 rows; 32 slots per (b, col)
#pragma unroll
    for (int n = 0; n < 4; ++n) {
      float mx = -3.0e38f;
#pragma unroll
      for (int m = 0; m < 4; ++m)
#pragma unroll
        for (int r = 0; r < 4; ++r) mx = fmaxf(mx, acc[m][n][r]);
      mx = fmaxf(mx, __shfl_xor(mx, 16, 64));
      mx = fmaxf(mx, __shfl_xor(mx, 32, 64));
      float l = 0.f;
#pragma unroll
      for (int m = 0; m < 4; ++m)
#pragma unroll
        for (int r = 0; r < 4; ++r) l += __expf(acc[m][n][r] - mx);
      l += __shfl_xor(l, 16, 64);
      l += __shfl_xor(l, 32, 64);
      if (lane < 16) {
        int col = tn * 128 + wc * 64 + n * 16 + lane;
        ps[((long)(b * 32 + tm * 2 + wr)) * N + col] = make_float2(mx, l);
      }
    }
  }
}

// ---- combine 32 per-tile partials -> (M_k, 1/L_k) ----
__global__ void k_stats_combine(const float2* __restrict__ ps, float2* __restrict__ st, int Kc) {
  const long i = (long)blockIdx.x * blockDim.x + threadIdx.x;  // over 8*Kc
  const int b = (int)(i / Kc), k = (int)(i % Kc);
  float M = -3.0e38f;
#pragma unroll
  for (int j = 0; j < 32; ++j) M = fmaxf(M, ps[((long)(b * 32 + j)) * Kc + k].x);
  float L = 0.f;
#pragma unroll
  for (int j = 0; j < 32; ++j) {
    float2 v = ps[((long)(b * 32 + j)) * Kc + k];
    L += v.y * __expf(v.x - M);
  }
  st[i] = make_float2(M, 1.0f / L);
}

// ---- P = exp(S - M_k) * invL_k -> fp16, 8 elems/thread (chunk) ----
__global__ void k_pcomp(const float* __restrict__ S, const float2* __restrict__ st,
                        unsigned short* __restrict__ P, int Kc) {
  const long i = (long)blockIdx.x * blockDim.x + threadIdx.x;
  const int kw = Kc >> 3;              // threads per row
  const long r = i / kw;               // row = b*2048 + q
  const int kb = (int)(i - r * kw) * 8;
  const int b = (int)(r >> 11);
  const float* sp = S + r * Kc + kb;
  float4 s0 = *(const float4*)sp;
  float4 s1 = *(const float4*)(sp + 4);
  const float2* tp = st + (long)b * Kc + kb;
  us8 o;
  float sv[8] = {s0.x, s0.y, s0.z, s0.w, s1.x, s1.y, s1.z, s1.w};
#pragma unroll
  for (int j = 0; j < 8; ++j) {
    float2 t = tp[j];
    o[j] = f2h(__expf(sv[j] - t.x) * t.y);
  }
  *(us8*)(P + r * Kc + kb) = o;
}

extern "C" void kernel_launch(void* const* d_in, const int* in_sizes, int n_in,
                              void* d_out, int out_size, void* d_ws, size_t ws_size,
                              hipStream_t stream) {
  const float* Q = (const float*)d_in[0];
  const float* Kp = (const float*)d_in[1];
  const float* V = (const float*)d_in[2];
  float* out = (float*)d_out;

  constexpr int Bb = 8, Qn = 2048, Kn = 2048, Dn = 1024;
  constexpr long QD = (long)Qn * Dn;

  // ---- tiered k-chunk size (full-GPU grids preferred) ----
  long Kc = 1024;
  for (;;) {
    size_t uKP = (size_t)Bb * Qn * Kc * 2;        // P (>= k16-chunk size)
    size_t need = (size_t)Bb * QD * 2              // q16
                + uKP                              // union(k16-chunk, P)
                + (size_t)Bb * Dn * Kc * 2         // vt chunk
                + (size_t)Bb * Qn * Kc * 4         // S chunk
                + (size_t)Bb * 32 * Kc * 8         // partial stats
                + (size_t)Bb * Kc * 8;             // final stats
    if (need <= ws_size || Kc == 256) break;
    Kc >>= 1;
  }
  const int nc = Kn / (int)Kc;

  char* w = (char*)d_ws;
  unsigned short* q16 = (unsigned short*)w; w += (size_t)Bb * QD * 2;
  unsigned short* kp  = (unsigned short*)w; w += (size_t)Bb * Qn * Kc * 2;  // k16c & P
  unsigned short* vt  = (unsigned short*)w; w += (size_t)Bb * Dn * Kc * 2;
  float* S            = (float*)w;          w += (size_t)Bb * Qn * Kc * 4;
  float2* ps          = (float2*)w;         w += (size_t)Bb * 32 * Kc * 8;
  float2* st          = (float2*)w;

  unsigned short* k16c = kp;   // alias: k16c dead before P is written
  unsigned short* P    = kp;

  // Q -> fp16 once
  k_cast16<<<(int)(Bb * QD / 8 / 256), 256, 0, stream>>>(Q, q16, Bb * QD / 8);

  for (int c = 0; c < nc; ++c) {
    const int k0c = c * (int)Kc;
    // K-chunk -> fp16 ; V-chunk -> VT fp16
    k_cast16c<<<(int)((long)Bb * Kc * Dn / 8 / 256), 256, 0, stream>>>(
        Kp, k16c, Kn, Dn, k0c, (int)Kc);
    k_transpose16<<<dim3((int)Kc / 64, Dn / 64, Bb), 256, 0, stream>>>(
        V, vt, Kn, Dn, k0c, (int)Kc);
    // S[:, :, chunk] = Q @ K_chunk^T  (+ column stats over q)
    k_gemm_bt<1, 0><<<dim3((int)Kc / 128, Qn / 128, Bb), 256, 0, stream>>>(
        q16, k16c, S, ps, (int)Kc, Dn, QD, (long)Kc * Dn, (long)Qn * Kc);
    k_stats_combine<<<Bb * (int)Kc / 256, 256, 0, stream>>>(ps, st, (int)Kc);
    // P = exp(S - M) * invL  (fp16, overwrites k16c slot)
    k_pcomp<<<(int)((long)Bb * Qn * (Kc / 8) / 256), 256, 0, stream>>>(
        S, st, P, (int)Kc);
    // out (+)= P_chunk @ V_chunk
    if (c == 0)
      k_gemm_bt<0, 0><<<dim3(Dn / 128, Qn / 128, Bb), 256, 0, stream>>>(
          P, vt, out, nullptr, Dn, (int)Kc, (long)Qn * Kc, (long)Dn * Kc, QD);
    else
      k_gemm_bt<0, 1><<<dim3(Dn / 128, Qn / 128, Bb), 256, 0, stream>>>(
          P, vt, out, nullptr, Dn, (int)Kc, (long)Qn * Kc, (long)Dn * Kc, QD);
  }
}